// Round 2
// baseline (7705.398 us; speedup 1.0000x reference)
//
#include <hip/hip_runtime.h>

#define CC 192
#define WF_BYTES (4*CC*CC*2)

typedef __attribute__((ext_vector_type(8))) short bf16x8;
typedef __attribute__((ext_vector_type(4))) float f32x4;

__device__ __forceinline__ unsigned short f2b(float f){
  unsigned u = __float_as_uint(f);
  return (unsigned short)((u + 0x7fffu + ((u >> 16) & 1u)) >> 16);
}
__device__ __forceinline__ unsigned pk2(float a, float b){
  return (unsigned)f2b(a) | ((unsigned)f2b(b) << 16);
}

// Fold conv1x1+in-proj (and out-proj+conv1x1) into 192x192 mats, bf16, [o][ci]
// row-major (MFMA-fragment friendly). Scale 1/sqrt(32) folded into Q mat+bias.
__global__ void fuse_weights(const float* __restrict__ wq, const float* __restrict__ bq,
                             const float* __restrict__ wk, const float* __restrict__ bk,
                             const float* __restrict__ wv, const float* __restrict__ bv,
                             const float* __restrict__ in_w, const float* __restrict__ in_b,
                             const float* __restrict__ out_w, const float* __restrict__ out_b,
                             const float* __restrict__ proj_w, const float* __restrict__ proj_b,
                             unsigned short* __restrict__ Wf, float* __restrict__ Bf)
{
  int mat = blockIdx.x / CC, o = blockIdx.x % CC, ci = threadIdx.x;
  const float *A, *Bm, *bs, *ba; int aoff, boff; float scale = 1.f;
  if (mat == 0){ A=in_w; aoff=0;    Bm=wq;    bs=bq;    ba=in_b;   boff=0;    scale=0.17677669529663687f; }
  else if (mat==1){ A=in_w; aoff=CC;   Bm=wk;    bs=bk;    ba=in_b;   boff=CC;   }
  else if (mat==2){ A=in_w; aoff=2*CC; Bm=wv;    bs=bv;    ba=in_b;   boff=2*CC; }
  else            { A=proj_w; aoff=0;  Bm=out_w; bs=out_b; ba=proj_b; boff=0;    }
  const float* ar = A + (size_t)(aoff + o) * CC;
  float acc = 0.f;
  for (int m = 0; m < CC; ++m) acc = fmaf(ar[m], Bm[m*CC + ci], acc);
  Wf[(mat*CC + o)*CC + ci] = f2b(acc * scale);
  if (ci == 0){
    float bacc = 0.f;
    for (int m = 0; m < CC; ++m) bacc = fmaf(ar[m], bs[m], bacc);
    Bf[mat*CC + o] = (bacc + ba[boff + o]) * scale;
  }
}

__global__ __launch_bounds__(512, 2) void win_attn(
    const float* __restrict__ q2d, const float* __restrict__ kv2d,
    const unsigned short* __restrict__ Wf, const float* __restrict__ Bf,
    float* __restrict__ out)
{
  __shared__ unsigned short Xb[64*200];   // X (q-win), then X (kv-win), then O  [tok][ch]
  __shared__ unsigned short Qb[64*200];   // Q [tok][ch] (pre-scaled)
  __shared__ unsigned short Kb[64*200];   // K [tok][ch]
  __shared__ unsigned short VTb[192*72];  // V^T [ch][tok]
  __shared__ unsigned short Pb[8*16*72];  // per-wave P [row16][t2 64]

  const int t = threadIdx.x;
  const int w = t >> 6, lane = t & 63, lr = lane & 15, lg = lane >> 4;
  const int bid = blockIdx.x;
  const int wid = (bid & 7) * 512 + (bid >> 3);      // XCD-chunked, bijective (4096=8*512)
  const int b = wid >> 10, l = wid & 1023;
  const int y0 = (l >> 5) << 3, x0 = (l & 31) << 3;
  const float* qb  = q2d  + (size_t)b * CC * 65536;
  const float* kvb = kv2d + (size_t)b * CC * 65536;
  const int mt = w & 3, nh = w >> 2;                 // proj decomposition: M-tile, N-half

  auto stageX = [&](const float* __restrict__ src){
    #pragma unroll
    for (int i = 0; i < 3; ++i){
      int lin = i*512 + t;
      int c2 = lin >> 4, tq = lin & 15;
      int tok0 = tq << 2;
      int gy = (y0 + (tok0 >> 3)) * 256 + x0 + (tok0 & 7);
      float4 va = *(const float4*)&src[(size_t)(2*c2)   * 65536 + gy];
      float4 vb = *(const float4*)&src[(size_t)(2*c2+1) * 65536 + gy];
      float fa[4] = {va.x, va.y, va.z, va.w};
      float fb[4] = {vb.x, vb.y, vb.z, vb.w};
      #pragma unroll
      for (int j = 0; j < 4; ++j)
        *(unsigned*)&Xb[(tok0 + j)*200 + 2*c2] = pk2(fa[j], fb[j]);
    }
  };

  // ---- Q projection ----
  stageX(qb);
  __syncthreads();
  {
    f32x4 cq[6] = {};
    #pragma unroll
    for (int k = 0; k < 6; ++k){
      bf16x8 a = *(const bf16x8*)&Xb[(mt*16 + lr)*200 + k*32 + lg*8];
      #pragma unroll
      for (int n = 0; n < 6; ++n){
        bf16x8 bw = *(const bf16x8*)&Wf[(size_t)(0*CC + nh*96 + n*16 + lr)*CC + k*32 + lg*8];
        cq[n] = __builtin_amdgcn_mfma_f32_16x16x32_bf16(a, bw, cq[n], 0, 0, 0);
      }
    }
    #pragma unroll
    for (int n = 0; n < 6; ++n){
      int ch = nh*96 + n*16 + lr;
      float bb = Bf[0*CC + ch];
      #pragma unroll
      for (int rr = 0; rr < 4; ++rr)
        Qb[(mt*16 + lg*4 + rr)*200 + ch] = f2b(cq[n][rr] + bb);
    }
  }
  __syncthreads();

  // ---- K and V projections (shared A-fragments) ----
  stageX(kvb);
  __syncthreads();
  {
    f32x4 ck[6] = {}, cv[6] = {};
    #pragma unroll
    for (int k = 0; k < 6; ++k){
      bf16x8 a = *(const bf16x8*)&Xb[(mt*16 + lr)*200 + k*32 + lg*8];
      #pragma unroll
      for (int n = 0; n < 6; ++n){
        bf16x8 bk_ = *(const bf16x8*)&Wf[(size_t)(1*CC + nh*96 + n*16 + lr)*CC + k*32 + lg*8];
        bf16x8 bv_ = *(const bf16x8*)&Wf[(size_t)(2*CC + nh*96 + n*16 + lr)*CC + k*32 + lg*8];
        ck[n] = __builtin_amdgcn_mfma_f32_16x16x32_bf16(a, bk_, ck[n], 0, 0, 0);
        cv[n] = __builtin_amdgcn_mfma_f32_16x16x32_bf16(a, bv_, cv[n], 0, 0, 0);
      }
    }
    #pragma unroll
    for (int n = 0; n < 6; ++n){
      int ch = nh*96 + n*16 + lr;
      float bbk = Bf[1*CC + ch], bbv = Bf[2*CC + ch];
      #pragma unroll
      for (int rr = 0; rr < 4; ++rr)
        Kb[(mt*16 + lg*4 + rr)*200 + ch] = f2b(ck[n][rr] + bbk);
      *(unsigned*)&VTb[ch*72 + mt*16 + lg*4]     = pk2(cv[n][0]+bbv, cv[n][1]+bbv);
      *(unsigned*)&VTb[ch*72 + mt*16 + lg*4 + 2] = pk2(cv[n][2]+bbv, cv[n][3]+bbv);
    }
  }
  __syncthreads();

  // ---- attention: 24 (head, row-quarter) tasks over 8 waves ----
  {
    const int pbase = w*1152 + lr*72;
    #pragma unroll
    for (int ti = 0; ti < 3; ++ti){
      int tau = w*3 + ti;
      int h = tau >> 2, r0 = (tau & 3) << 4;
      // S^T = K · Q^T  (M=64 t2, N=16 rows, K=32=hd)
      f32x4 st[4] = {};
      bf16x8 bq_ = *(const bf16x8*)&Qb[(r0 + lr)*200 + h*32 + lg*8];
      #pragma unroll
      for (int m = 0; m < 4; ++m){
        bf16x8 a = *(const bf16x8*)&Kb[(m*16 + lr)*200 + h*32 + lg*8];
        st[m] = __builtin_amdgcn_mfma_f32_16x16x32_bf16(a, bq_, st[m], 0, 0, 0);
      }
      // wave-parallel softmax over t2 (16 vals/lane + lanes l^16, l^32 share row)
      float mx = st[0][0];
      #pragma unroll
      for (int m = 0; m < 4; ++m)
        #pragma unroll
        for (int rr = 0; rr < 4; ++rr) mx = fmaxf(mx, st[m][rr]);
      mx = fmaxf(mx, __shfl_xor(mx, 16));
      mx = fmaxf(mx, __shfl_xor(mx, 32));
      float p[16]; float s = 0.f;
      #pragma unroll
      for (int m = 0; m < 4; ++m)
        #pragma unroll
        for (int rr = 0; rr < 4; ++rr){ float e = __expf(st[m][rr] - mx); p[m*4+rr] = e; s += e; }
      s += __shfl_xor(s, 16); s += __shfl_xor(s, 32);
      float inv = 1.f / s;
      #pragma unroll
      for (int m = 0; m < 4; ++m){
        *(unsigned*)&Pb[pbase + m*16 + lg*4]     = pk2(p[m*4+0]*inv, p[m*4+1]*inv);
        *(unsigned*)&Pb[pbase + m*16 + lg*4 + 2] = pk2(p[m*4+2]*inv, p[m*4+3]*inv);
      }
      // O = P · V  (M=16 rows, N=32 hd, K=64 t2); B from V^T
      f32x4 o0 = {}, o1 = {};
      #pragma unroll
      for (int kt = 0; kt < 2; ++kt){
        bf16x8 ap  = *(const bf16x8*)&Pb[pbase + kt*32 + lg*8];
        bf16x8 bv0 = *(const bf16x8*)&VTb[(h*32 + lr)*72      + kt*32 + lg*8];
        bf16x8 bv1 = *(const bf16x8*)&VTb[(h*32 + 16 + lr)*72 + kt*32 + lg*8];
        o0 = __builtin_amdgcn_mfma_f32_16x16x32_bf16(ap, bv0, o0, 0, 0, 0);
        o1 = __builtin_amdgcn_mfma_f32_16x16x32_bf16(ap, bv1, o1, 0, 0, 0);
      }
      #pragma unroll
      for (int rr = 0; rr < 4; ++rr){
        int tok = r0 + lg*4 + rr;
        Xb[tok*200 + h*32 + lr]      = f2b(o0[rr]);
        Xb[tok*200 + h*32 + 16 + lr] = f2b(o1[rr]);
      }
    }
  }
  __syncthreads();

  // ---- output projection: E2^T = Wo_f · O^T (M=192 o, N=64 tok, K=192) ----
  {
    f32x4 eo[3][2] = {};
    #pragma unroll
    for (int k = 0; k < 6; ++k){
      bf16x8 bo[4];
      #pragma unroll
      for (int nt = 0; nt < 4; ++nt)
        bo[nt] = *(const bf16x8*)&Xb[(nt*16 + lr)*200 + k*32 + lg*8];
      #pragma unroll
      for (int u = 0; u < 3; ++u){
        int g = w*3 + u; int mto = g >> 1, np = g & 1;
        bf16x8 aw = *(const bf16x8*)&Wf[(size_t)(3*CC + mto*16 + lr)*CC + k*32 + lg*8];
        eo[u][0] = __builtin_amdgcn_mfma_f32_16x16x32_bf16(aw, bo[np*2+0], eo[u][0], 0, 0, 0);
        eo[u][1] = __builtin_amdgcn_mfma_f32_16x16x32_bf16(aw, bo[np*2+1], eo[u][1], 0, 0, 0);
      }
    }
    #pragma unroll
    for (int u = 0; u < 3; ++u){
      int g = w*3 + u; int mto = g >> 1, np = g & 1;
      #pragma unroll
      for (int j = 0; j < 2; ++j){
        #pragma unroll
        for (int rr = 0; rr < 4; ++rr){
          int o = mto*16 + lg*4 + rr;
          int tok = (np*2 + j)*16 + lr;
          size_t gaddr = (size_t)(b*CC + o)*65536 + (size_t)(y0 + (tok >> 3))*256 + x0 + (tok & 7);
          out[gaddr] = eo[u][j][rr] + Bf[3*CC + o] + q2d[gaddr];
        }
      }
    }
  }
}

extern "C" void kernel_launch(void* const* d_in, const int* in_sizes, int n_in,
                              void* d_out, int out_size, void* d_ws, size_t ws_size,
                              hipStream_t stream)
{
  const float* q2d    = (const float*)d_in[0];
  const float* kv2d   = (const float*)d_in[1];
  const float* wq     = (const float*)d_in[2];
  const float* bq     = (const float*)d_in[3];
  const float* wk     = (const float*)d_in[4];
  const float* bk     = (const float*)d_in[5];
  const float* wv     = (const float*)d_in[6];
  const float* bv     = (const float*)d_in[7];
  const float* in_w   = (const float*)d_in[8];
  const float* in_b   = (const float*)d_in[9];
  const float* out_w  = (const float*)d_in[10];
  const float* out_b  = (const float*)d_in[11];
  const float* proj_w = (const float*)d_in[12];
  const float* proj_b = (const float*)d_in[13];

  unsigned short* Wf = (unsigned short*)d_ws;
  float* Bf = (float*)((char*)d_ws + WF_BYTES);
  float* out = (float*)d_out;

  fuse_weights<<<4*CC, CC, 0, stream>>>(wq,bq,wk,bk,wv,bv,in_w,in_b,
                                        out_w,out_b,proj_w,proj_b, Wf, Bf);
  win_attn<<<4096, 512, 0, stream>>>(q2d, kv2d, Wf, Bf, out);
}

// Round 3
// 7418.612 us; speedup vs baseline: 1.0387x; 1.0387x over previous
//
#include <hip/hip_runtime.h>

#define CC 192
#define WFRAG_USHORTS (4*6*12*512)

typedef __attribute__((ext_vector_type(8))) short bf16x8;
typedef __attribute__((ext_vector_type(4))) float f32x4;

__device__ __forceinline__ unsigned short f2b(float f){
  unsigned u = __float_as_uint(f);
  return (unsigned short)((u + 0x7fffu + ((u >> 16) & 1u)) >> 16);
}
__device__ __forceinline__ unsigned pk2(float a, float b){
  return (unsigned)f2b(a) | ((unsigned)f2b(b) << 16);
}

// Weights packed in MFMA-fragment order: Wfrag[mat][k][n][lane][8] so one
// wave B-fragment = one contiguous 1KB block (coalesced 16B/lane load).
__global__ void fuse_weights(const float* __restrict__ wq, const float* __restrict__ bq,
                             const float* __restrict__ wk, const float* __restrict__ bk,
                             const float* __restrict__ wv, const float* __restrict__ bv,
                             const float* __restrict__ in_w, const float* __restrict__ in_b,
                             const float* __restrict__ out_w, const float* __restrict__ out_b,
                             const float* __restrict__ proj_w, const float* __restrict__ proj_b,
                             unsigned short* __restrict__ Wf, float* __restrict__ Bf)
{
  int mat = blockIdx.x / CC, o = blockIdx.x % CC, ci = threadIdx.x;
  const float *A, *Bm, *bs, *ba; int aoff, boff; float scale = 1.f;
  if (mat == 0){ A=in_w; aoff=0;    Bm=wq;    bs=bq;    ba=in_b;   boff=0;    scale=0.17677669529663687f; }
  else if (mat==1){ A=in_w; aoff=CC;   Bm=wk;    bs=bk;    ba=in_b;   boff=CC;   }
  else if (mat==2){ A=in_w; aoff=2*CC; Bm=wv;    bs=bv;    ba=in_b;   boff=2*CC; }
  else            { A=proj_w; aoff=0;  Bm=out_w; bs=out_b; ba=proj_b; boff=0;    }
  const float* ar = A + (size_t)(aoff + o) * CC;
  float acc = 0.f;
  for (int m = 0; m < CC; ++m) acc = fmaf(ar[m], Bm[m*CC + ci], acc);
  int k = ci >> 5, n = o >> 4, lgv = (ci >> 3) & 3, e = ci & 7;
  int lane = (o & 15) | (lgv << 4);
  Wf[(((mat*6 + k)*12 + n) << 9) + lane*8 + e] = f2b(acc * scale);
  if (ci == 0){
    float bacc = 0.f;
    for (int m = 0; m < CC; ++m) bacc = fmaf(ar[m], bs[m], bacc);
    Bf[mat*CC + o] = (bacc + ba[boff + o]) * scale;
  }
}

__global__ __launch_bounds__(512, 2) void win_attn(
    const float* __restrict__ q2d, const float* __restrict__ kv2d,
    const unsigned short* __restrict__ Wf, const float* __restrict__ Bf,
    float* __restrict__ out)
{
  __shared__ unsigned short B1[64*200];   // Xq, then per-wave P scratch
  __shared__ unsigned short B2[64*200];   // Xkv, then O [tok][ch]
  __shared__ unsigned short Qb[64*200];
  __shared__ unsigned short Kb[64*200];
  __shared__ unsigned short VTb[192*72];

  const int t = threadIdx.x;
  const int w = t >> 6, lane = t & 63, lr = lane & 15, lg = lane >> 4;
  const int bid = blockIdx.x;
  const int wid = (bid & 7) * 512 + (bid >> 3);      // XCD-chunked, bijective
  const int b = wid >> 10, l = wid & 1023;
  const int y0 = (l >> 5) << 3, x0 = (l & 31) << 3;
  const float* qb  = q2d  + (size_t)b * CC * 65536;
  const float* kvb = kv2d + (size_t)b * CC * 65536;

  auto stageX = [&](const float* __restrict__ src, unsigned short* __restrict__ dst){
    #pragma unroll
    for (int i = 0; i < 3; ++i){
      int lin = i*512 + t;
      int c2 = lin >> 4, tq = lin & 15;
      int tok0 = tq << 2;
      int gy = (y0 + (tok0 >> 3)) * 256 + x0 + (tok0 & 7);
      float4 va = *(const float4*)&src[(size_t)(2*c2)   * 65536 + gy];
      float4 vb = *(const float4*)&src[(size_t)(2*c2+1) * 65536 + gy];
      float fa[4] = {va.x, va.y, va.z, va.w};
      float fb[4] = {vb.x, vb.y, vb.z, vb.w};
      #pragma unroll
      for (int j = 0; j < 4; ++j)
        *(unsigned*)&dst[(tok0 + j)*200 + 2*c2] = pk2(fa[j], fb[j]);
    }
  };

  // ---- P0: stage both windows ----
  stageX(qb, B1);
  stageX(kvb, B2);
  __syncthreads();

  // ---- P1: all projections as 36 units (proj, n-tile), M=64 per unit ----
  {
    int pj[5], nn[5];
    #pragma unroll
    for (int ui = 0; ui < 5; ++ui){
      int u = (ui < 4) ? (w*4 + ui) : (32 + w);
      pj[ui] = u / 12; nn[ui] = u - pj[ui]*12;
    }
    f32x4 acc[5][4] = {};
    #pragma unroll
    for (int k = 0; k < 6; ++k){
      bf16x8 aq[4], akv[4];
      #pragma unroll
      for (int m = 0; m < 4; ++m){
        aq[m]  = *(const bf16x8*)&B1[(m*16 + lr)*200 + k*32 + lg*8];
        akv[m] = *(const bf16x8*)&B2[(m*16 + lr)*200 + k*32 + lg*8];
      }
      #pragma unroll
      for (int ui = 0; ui < 5; ++ui){
        if (ui == 4 && w >= 4) continue;
        bf16x8 bw = *(const bf16x8*)&Wf[(((pj[ui]*6 + k)*12 + nn[ui]) << 9) + lane*8];
        if (pj[ui] == 0){
          #pragma unroll
          for (int m = 0; m < 4; ++m)
            acc[ui][m] = __builtin_amdgcn_mfma_f32_16x16x32_bf16(aq[m], bw, acc[ui][m], 0, 0, 0);
        } else {
          #pragma unroll
          for (int m = 0; m < 4; ++m)
            acc[ui][m] = __builtin_amdgcn_mfma_f32_16x16x32_bf16(akv[m], bw, acc[ui][m], 0, 0, 0);
        }
      }
    }
    #pragma unroll
    for (int ui = 0; ui < 5; ++ui){
      if (ui == 4 && w >= 4) continue;
      int ch = nn[ui]*16 + lr;
      float bb = Bf[pj[ui]*CC + ch];
      if (pj[ui] == 0){
        #pragma unroll
        for (int m = 0; m < 4; ++m)
          #pragma unroll
          for (int rr = 0; rr < 4; ++rr)
            Qb[(m*16 + lg*4 + rr)*200 + ch] = f2b(acc[ui][m][rr] + bb);
      } else if (pj[ui] == 1){
        #pragma unroll
        for (int m = 0; m < 4; ++m)
          #pragma unroll
          for (int rr = 0; rr < 4; ++rr)
            Kb[(m*16 + lg*4 + rr)*200 + ch] = f2b(acc[ui][m][rr] + bb);
      } else {
        #pragma unroll
        for (int m = 0; m < 4; ++m){
          *(unsigned*)&VTb[ch*72 + m*16 + lg*4]     = pk2(acc[ui][m][0]+bb, acc[ui][m][1]+bb);
          *(unsigned*)&VTb[ch*72 + m*16 + lg*4 + 2] = pk2(acc[ui][m][2]+bb, acc[ui][m][3]+bb);
        }
      }
    }
  }
  __syncthreads();

  // ---- P2: attention, 24 (head, row-quarter) tasks; P in B1, O into B2 ----
  {
    unsigned short* Pb = B1;
    const int pbase = w*1152 + lr*72;
    #pragma unroll
    for (int ti = 0; ti < 3; ++ti){
      int tau = w*3 + ti;
      int h = tau >> 2, r0 = (tau & 3) << 4;
      f32x4 st[4] = {};
      bf16x8 bq_ = *(const bf16x8*)&Qb[(r0 + lr)*200 + h*32 + lg*8];
      #pragma unroll
      for (int m = 0; m < 4; ++m){
        bf16x8 a = *(const bf16x8*)&Kb[(m*16 + lr)*200 + h*32 + lg*8];
        st[m] = __builtin_amdgcn_mfma_f32_16x16x32_bf16(a, bq_, st[m], 0, 0, 0);
      }
      float mx = st[0][0];
      #pragma unroll
      for (int m = 0; m < 4; ++m)
        #pragma unroll
        for (int rr = 0; rr < 4; ++rr) mx = fmaxf(mx, st[m][rr]);
      mx = fmaxf(mx, __shfl_xor(mx, 16));
      mx = fmaxf(mx, __shfl_xor(mx, 32));
      float p[16]; float s = 0.f;
      #pragma unroll
      for (int m = 0; m < 4; ++m)
        #pragma unroll
        for (int rr = 0; rr < 4; ++rr){ float e = __expf(st[m][rr] - mx); p[m*4+rr] = e; s += e; }
      s += __shfl_xor(s, 16); s += __shfl_xor(s, 32);
      float inv = 1.f / s;
      #pragma unroll
      for (int m = 0; m < 4; ++m){
        *(unsigned*)&Pb[pbase + m*16 + lg*4]     = pk2(p[m*4+0]*inv, p[m*4+1]*inv);
        *(unsigned*)&Pb[pbase + m*16 + lg*4 + 2] = pk2(p[m*4+2]*inv, p[m*4+3]*inv);
      }
      f32x4 o0 = {}, o1 = {};
      #pragma unroll
      for (int kt = 0; kt < 2; ++kt){
        bf16x8 ap  = *(const bf16x8*)&Pb[pbase + kt*32 + lg*8];
        bf16x8 bv0 = *(const bf16x8*)&VTb[(h*32 + lr)*72      + kt*32 + lg*8];
        bf16x8 bv1 = *(const bf16x8*)&VTb[(h*32 + 16 + lr)*72 + kt*32 + lg*8];
        o0 = __builtin_amdgcn_mfma_f32_16x16x32_bf16(ap, bv0, o0, 0, 0, 0);
        o1 = __builtin_amdgcn_mfma_f32_16x16x32_bf16(ap, bv1, o1, 0, 0, 0);
      }
      #pragma unroll
      for (int rr = 0; rr < 4; ++rr){
        int tok = r0 + lg*4 + rr;
        B2[tok*200 + h*32 + lr]      = f2b(o0[rr]);
        B2[tok*200 + h*32 + 16 + lr] = f2b(o1[rr]);
      }
    }
  }
  __syncthreads();

  // ---- P3: output projection E2^T = Wo_f · O^T, + bias + residual ----
  {
    f32x4 eo[3][2] = {};
    #pragma unroll
    for (int k = 0; k < 6; ++k){
      bf16x8 bo[4];
      #pragma unroll
      for (int nt = 0; nt < 4; ++nt)
        bo[nt] = *(const bf16x8*)&B2[(nt*16 + lr)*200 + k*32 + lg*8];
      #pragma unroll
      for (int u = 0; u < 3; ++u){
        int g = w*3 + u; int mto = g >> 1, np = g & 1;
        bf16x8 aw = *(const bf16x8*)&Wf[((18 + k)*12 + mto)*512 + lane*8];
        eo[u][0] = __builtin_amdgcn_mfma_f32_16x16x32_bf16(aw, bo[np*2+0], eo[u][0], 0, 0, 0);
        eo[u][1] = __builtin_amdgcn_mfma_f32_16x16x32_bf16(aw, bo[np*2+1], eo[u][1], 0, 0, 0);
      }
    }
    #pragma unroll
    for (int u = 0; u < 3; ++u){
      int g = w*3 + u; int mto = g >> 1, np = g & 1;
      #pragma unroll
      for (int j = 0; j < 2; ++j){
        #pragma unroll
        for (int rr = 0; rr < 4; ++rr){
          int o = mto*16 + lg*4 + rr;
          int tok = (np*2 + j)*16 + lr;
          size_t gaddr = (size_t)(b*CC + o)*65536 + (size_t)(y0 + (tok >> 3))*256 + x0 + (tok & 7);
          out[gaddr] = eo[u][j][rr] + Bf[3*CC + o] + q2d[gaddr];
        }
      }
    }
  }
}

extern "C" void kernel_launch(void* const* d_in, const int* in_sizes, int n_in,
                              void* d_out, int out_size, void* d_ws, size_t ws_size,
                              hipStream_t stream)
{
  const float* q2d    = (const float*)d_in[0];
  const float* kv2d   = (const float*)d_in[1];
  const float* wq     = (const float*)d_in[2];
  const float* bq     = (const float*)d_in[3];
  const float* wk     = (const float*)d_in[4];
  const float* bk     = (const float*)d_in[5];
  const float* wv     = (const float*)d_in[6];
  const float* bv     = (const float*)d_in[7];
  const float* in_w   = (const float*)d_in[8];
  const float* in_b   = (const float*)d_in[9];
  const float* out_w  = (const float*)d_in[10];
  const float* out_b  = (const float*)d_in[11];
  const float* proj_w = (const float*)d_in[12];
  const float* proj_b = (const float*)d_in[13];

  unsigned short* Wf = (unsigned short*)d_ws;
  float* Bf = (float*)((char*)d_ws + WFRAG_USHORTS*2);
  float* out = (float*)d_out;

  fuse_weights<<<4*CC, CC, 0, stream>>>(wq,bq,wk,bk,wv,bv,in_w,in_b,
                                        out_w,out_b,proj_w,proj_b, Wf, Bf);
  win_attn<<<4096, 512, 0, stream>>>(q2d, kv2d, Wf, Bf, out);
}

// Round 4
// 453.268 us; speedup vs baseline: 16.9997x; 16.3670x over previous
//
#include <hip/hip_runtime.h>

#define CC 192
#define WFRAG_USHORTS (4*6*12*512)

typedef __attribute__((ext_vector_type(8))) short bf16x8;
typedef __attribute__((ext_vector_type(4))) float f32x4;

__device__ __forceinline__ unsigned short f2b(float f){
  unsigned u = __float_as_uint(f);
  return (unsigned short)((u + 0x7fffu + ((u >> 16) & 1u)) >> 16);
}
__device__ __forceinline__ unsigned pk2(float a, float b){
  return (unsigned)f2b(a) | ((unsigned)f2b(b) << 16);
}
// [row][ch] buffers, stride 200 ushorts; XOR-swizzle ch by row (bijective in-row)
__device__ __forceinline__ int sx(int row, int ch){
  return row*200 + (ch ^ ((row & 7) << 3));
}
// [row][tok] buffers, stride 72 ushorts
__device__ __forceinline__ int sv(int row, int tok){
  return row*72 + (tok ^ ((row & 7) << 3));
}

// Weights packed in MFMA-fragment order: Wf[mat][k][n][lane][8]; one wave
// B/A-fragment = one contiguous 1KB block. 1/sqrt(32) folded into Q mat+bias.
__global__ void fuse_weights(const float* __restrict__ wq, const float* __restrict__ bq,
                             const float* __restrict__ wk, const float* __restrict__ bk,
                             const float* __restrict__ wv, const float* __restrict__ bv,
                             const float* __restrict__ in_w, const float* __restrict__ in_b,
                             const float* __restrict__ out_w, const float* __restrict__ out_b,
                             const float* __restrict__ proj_w, const float* __restrict__ proj_b,
                             unsigned short* __restrict__ Wf, float* __restrict__ Bf)
{
  int mat = blockIdx.x / CC, o = blockIdx.x % CC, ci = threadIdx.x;
  const float *A, *Bm, *bs, *ba; int aoff, boff; float scale = 1.f;
  if (mat == 0){ A=in_w; aoff=0;    Bm=wq;    bs=bq;    ba=in_b;   boff=0;    scale=0.17677669529663687f; }
  else if (mat==1){ A=in_w; aoff=CC;   Bm=wk;    bs=bk;    ba=in_b;   boff=CC;   }
  else if (mat==2){ A=in_w; aoff=2*CC; Bm=wv;    bs=bv;    ba=in_b;   boff=2*CC; }
  else            { A=proj_w; aoff=0;  Bm=out_w; bs=out_b; ba=proj_b; boff=0;    }
  const float* ar = A + (size_t)(aoff + o) * CC;
  float acc = 0.f;
  for (int m = 0; m < CC; ++m) acc = fmaf(ar[m], Bm[m*CC + ci], acc);
  int k = ci >> 5, n = o >> 4, lgv = (ci >> 3) & 3, e = ci & 7;
  int lane = (o & 15) | (lgv << 4);
  Wf[(((mat*6 + k)*12 + n) << 9) + lane*8 + e] = f2b(acc * scale);
  if (ci == 0){
    float bacc = 0.f;
    for (int m = 0; m < CC; ++m) bacc = fmaf(ar[m], bs[m], bacc);
    Bf[mat*CC + o] = (bacc + ba[boff + o]) * scale;
  }
}

__global__ __launch_bounds__(256, 1) void win_attn(
    const float* __restrict__ q2d, const float* __restrict__ kv2d,
    const unsigned short* __restrict__ Wf, const float* __restrict__ Bf,
    float* __restrict__ out)
{
  __shared__ unsigned short B1[64*200];   // Xq -> O [tok][ch]
  __shared__ unsigned short B2[64*200];   // Xkv -> per-wave P scratch
  __shared__ unsigned short Qb[64*200];   // [tok][ch], pre-scaled
  __shared__ unsigned short Kb[64*200];   // [tok][ch]
  __shared__ unsigned short VT[192*72];   // V^T [ch][tok]

  const int t = threadIdx.x;
  const int w = t >> 6, lane = t & 63, lr = lane & 15, lg = lane >> 4;
  const int bid = blockIdx.x;
  const int wid = (bid & 7) * 512 + (bid >> 3);   // XCD-chunked, bijective
  const int b = wid >> 10, l = wid & 1023;
  const int y0 = (l >> 5) << 3, x0 = (l & 31) << 3;
  const float* qsrc  = q2d  + (size_t)b * CC * 65536;
  const float* kvsrc = kv2d + (size_t)b * CC * 65536;
  const int n0 = w * 3;   // this wave's fixed 3-tile (48-channel) slice

  auto stage = [&](const float* __restrict__ src, unsigned short* __restrict__ dst){
    #pragma unroll
    for (int i = 0; i < 6; ++i){
      int lin = i*256 + t;
      int c2 = lin >> 4, tok0 = (lin & 15) << 2;
      int gy = (y0 + (tok0 >> 3)) * 256 + x0 + (tok0 & 7);
      float4 va = *(const float4*)&src[(size_t)(2*c2)   * 65536 + gy];
      float4 vb = *(const float4*)&src[(size_t)(2*c2+1) * 65536 + gy];
      float fa[4] = {va.x, va.y, va.z, va.w};
      float fb[4] = {vb.x, vb.y, vb.z, vb.w};
      #pragma unroll
      for (int j = 0; j < 4; ++j)
        *(unsigned*)&dst[sx(tok0 + j, 2*c2)] = pk2(fa[j], fb[j]);
    }
  };

  stage(qsrc, B1);
  stage(kvsrc, B2);
  __syncthreads();

  // ---- projections: every wave identical code, fixed channel slice ----
  auto projQK = [&](const unsigned short* __restrict__ Xs, int mat,
                    unsigned short* __restrict__ dst){
    f32x4 acc[3][4] = {};
    #pragma unroll
    for (int k = 0; k < 6; ++k){
      bf16x8 a[4];
      #pragma unroll
      for (int m = 0; m < 4; ++m)
        a[m] = *(const bf16x8*)&Xs[sx(m*16 + lr, k*32 + lg*8)];
      #pragma unroll
      for (int u = 0; u < 3; ++u){
        bf16x8 bw = *(const bf16x8*)&Wf[(((mat*6 + k)*12 + n0 + u) << 9) + lane*8];
        #pragma unroll
        for (int m = 0; m < 4; ++m)
          acc[u][m] = __builtin_amdgcn_mfma_f32_16x16x32_bf16(a[m], bw, acc[u][m], 0, 0, 0);
      }
    }
    #pragma unroll
    for (int u = 0; u < 3; ++u){
      int ch = (n0 + u)*16 + lr;
      float bb = Bf[mat*CC + ch];
      #pragma unroll
      for (int m = 0; m < 4; ++m)
        #pragma unroll
        for (int rr = 0; rr < 4; ++rr)
          dst[sx(m*16 + lg*4 + rr, ch)] = f2b(acc[u][m][rr] + bb);
    }
  };

  projQK(B1, 0, Qb);
  projQK(B2, 1, Kb);

  { // V projection -> VT (transposed store)
    f32x4 acc[3][4] = {};
    #pragma unroll
    for (int k = 0; k < 6; ++k){
      bf16x8 a[4];
      #pragma unroll
      for (int m = 0; m < 4; ++m)
        a[m] = *(const bf16x8*)&B2[sx(m*16 + lr, k*32 + lg*8)];
      #pragma unroll
      for (int u = 0; u < 3; ++u){
        bf16x8 bw = *(const bf16x8*)&Wf[(((12 + k)*12 + n0 + u) << 9) + lane*8];
        #pragma unroll
        for (int m = 0; m < 4; ++m)
          acc[u][m] = __builtin_amdgcn_mfma_f32_16x16x32_bf16(a[m], bw, acc[u][m], 0, 0, 0);
      }
    }
    #pragma unroll
    for (int u = 0; u < 3; ++u){
      int row = (n0 + u)*16 + lr;
      float bb = Bf[2*CC + row];
      #pragma unroll
      for (int m = 0; m < 4; ++m){
        *(unsigned*)&VT[sv(row, m*16 + lg*4)]     = pk2(acc[u][m][0] + bb, acc[u][m][1] + bb);
        *(unsigned*)&VT[sv(row, m*16 + lg*4 + 2)] = pk2(acc[u][m][2] + bb, acc[u][m][3] + bb);
      }
    }
  }
  __syncthreads();

  // ---- attention: wave w owns q-rows r0..r0+15, all 6 heads ----
  {
    const int r0 = w * 16;
    unsigned short* P = B2 + w*1152;    // 16 rows x 72, per-wave
    const int psw = (lr & 7) << 3;
    #pragma unroll
    for (int h = 0; h < 6; ++h){
      f32x4 st[4] = {};
      bf16x8 bq_ = *(const bf16x8*)&Qb[sx(r0 + lr, h*32 + lg*8)];
      #pragma unroll
      for (int m = 0; m < 4; ++m){
        bf16x8 a = *(const bf16x8*)&Kb[sx(m*16 + lr, h*32 + lg*8)];
        st[m] = __builtin_amdgcn_mfma_f32_16x16x32_bf16(a, bq_, st[m], 0, 0, 0);
      }
      float mx = st[0][0];
      #pragma unroll
      for (int m = 0; m < 4; ++m)
        #pragma unroll
        for (int rr = 0; rr < 4; ++rr) mx = fmaxf(mx, st[m][rr]);
      mx = fmaxf(mx, __shfl_xor(mx, 16));
      mx = fmaxf(mx, __shfl_xor(mx, 32));
      float p[16]; float s = 0.f;
      #pragma unroll
      for (int m = 0; m < 4; ++m)
        #pragma unroll
        for (int rr = 0; rr < 4; ++rr){ float e = __expf(st[m][rr] - mx); p[m*4+rr] = e; s += e; }
      s += __shfl_xor(s, 16); s += __shfl_xor(s, 32);
      float inv = 1.f / s;
      #pragma unroll
      for (int m = 0; m < 4; ++m){
        int c0 = m*16 + lg*4;
        *(unsigned*)&P[lr*72 + ((c0)     ^ psw)] = pk2(p[m*4+0]*inv, p[m*4+1]*inv);
        *(unsigned*)&P[lr*72 + ((c0 + 2) ^ psw)] = pk2(p[m*4+2]*inv, p[m*4+3]*inv);
      }
      f32x4 o0 = {}, o1 = {};
      #pragma unroll
      for (int kt = 0; kt < 2; ++kt){
        bf16x8 ap = *(const bf16x8*)&P[lr*72 + ((kt*32 + lg*8) ^ psw)];
        bf16x8 v0 = *(const bf16x8*)&VT[sv(h*32 + lr,      kt*32 + lg*8)];
        bf16x8 v1 = *(const bf16x8*)&VT[sv(h*32 + 16 + lr, kt*32 + lg*8)];
        o0 = __builtin_amdgcn_mfma_f32_16x16x32_bf16(ap, v0, o0, 0, 0, 0);
        o1 = __builtin_amdgcn_mfma_f32_16x16x32_bf16(ap, v1, o1, 0, 0, 0);
      }
      #pragma unroll
      for (int rr = 0; rr < 4; ++rr){
        int tok = r0 + lg*4 + rr;
        B1[sx(tok, h*32 + lr)]      = f2b(o0[rr]);
        B1[sx(tok, h*32 + 16 + lr)] = f2b(o1[rr]);
      }
    }
  }
  __syncthreads();

  // ---- out-proj: E2^T = Wo_f * O^T; wave w owns out-channel tiles w*3..w*3+2 ----
  {
    f32x4 eo[3][4] = {};
    #pragma unroll
    for (int k = 0; k < 6; ++k){
      bf16x8 bo[4];
      #pragma unroll
      for (int nt = 0; nt < 4; ++nt)
        bo[nt] = *(const bf16x8*)&B1[sx(nt*16 + lr, k*32 + lg*8)];
      #pragma unroll
      for (int u = 0; u < 3; ++u){
        bf16x8 aw = *(const bf16x8*)&Wf[(((18 + k)*12 + n0 + u) << 9) + lane*8];
        #pragma unroll
        for (int nt = 0; nt < 4; ++nt)
          eo[u][nt] = __builtin_amdgcn_mfma_f32_16x16x32_bf16(aw, bo[nt], eo[u][nt], 0, 0, 0);
      }
    }
    #pragma unroll
    for (int u = 0; u < 3; ++u){
      #pragma unroll
      for (int rr = 0; rr < 4; ++rr){
        int o = (n0 + u)*16 + lg*4 + rr;
        float bb = Bf[3*CC + o];
        #pragma unroll
        for (int nt = 0; nt < 4; ++nt){
          int tok = nt*16 + lr;
          size_t g = (size_t)(b*CC + o)*65536 + (size_t)(y0 + (tok >> 3))*256 + x0 + (tok & 7);
          out[g] = eo[u][nt][rr] + bb + q2d[g];
        }
      }
    }
  }
}

extern "C" void kernel_launch(void* const* d_in, const int* in_sizes, int n_in,
                              void* d_out, int out_size, void* d_ws, size_t ws_size,
                              hipStream_t stream)
{
  const float* q2d    = (const float*)d_in[0];
  const float* kv2d   = (const float*)d_in[1];
  const float* wq     = (const float*)d_in[2];
  const float* bq     = (const float*)d_in[3];
  const float* wk     = (const float*)d_in[4];
  const float* bk     = (const float*)d_in[5];
  const float* wv     = (const float*)d_in[6];
  const float* bv     = (const float*)d_in[7];
  const float* in_w   = (const float*)d_in[8];
  const float* in_b   = (const float*)d_in[9];
  const float* out_w  = (const float*)d_in[10];
  const float* out_b  = (const float*)d_in[11];
  const float* proj_w = (const float*)d_in[12];
  const float* proj_b = (const float*)d_in[13];

  unsigned short* Wf = (unsigned short*)d_ws;
  float* Bf = (float*)((char*)d_ws + WFRAG_USHORTS*2);
  float* out = (float*)d_out;

  fuse_weights<<<4*CC, CC, 0, stream>>>(wq,bq,wk,bk,wv,bv,in_w,in_b,
                                        out_w,out_b,proj_w,proj_b, Wf, Bf);
  win_attn<<<4096, 256, 0, stream>>>(q2d, kv2d, Wf, Bf, out);
}

// Round 5
// 328.648 us; speedup vs baseline: 23.4457x; 1.3792x over previous
//
#include <hip/hip_runtime.h>

#define CC 192
#define WFRAG_USHORTS (4*6*12*512)
#define SX 202   // [tok][ch] stride (ushorts): 404B = 101 dwords == 5 mod 32

typedef __attribute__((ext_vector_type(8))) short bf16x8;
typedef __attribute__((ext_vector_type(4))) float f32x4;

__device__ __forceinline__ unsigned short f2b(float f){
  unsigned u = __float_as_uint(f);
  return (unsigned short)((u + 0x7fffu + ((u >> 16) & 1u)) >> 16);
}
__device__ __forceinline__ unsigned pk2(float a, float b){
  return (unsigned)f2b(a) | ((unsigned)f2b(b) << 16);
}

// Weights packed in MFMA-fragment order: Wf[mat][k][n][lane][8]; one wave
// B/A-fragment = one contiguous 1KB block. 1/sqrt(32) folded into Q mat+bias.
__global__ void fuse_weights(const float* __restrict__ wq, const float* __restrict__ bq,
                             const float* __restrict__ wk, const float* __restrict__ bk,
                             const float* __restrict__ wv, const float* __restrict__ bv,
                             const float* __restrict__ in_w, const float* __restrict__ in_b,
                             const float* __restrict__ out_w, const float* __restrict__ out_b,
                             const float* __restrict__ proj_w, const float* __restrict__ proj_b,
                             unsigned short* __restrict__ Wf, float* __restrict__ Bf)
{
  int mat = blockIdx.x / CC, o = blockIdx.x % CC, ci = threadIdx.x;
  const float *A, *Bm, *bs, *ba; int aoff, boff; float scale = 1.f;
  if (mat == 0){ A=in_w; aoff=0;    Bm=wq;    bs=bq;    ba=in_b;   boff=0;    scale=0.17677669529663687f; }
  else if (mat==1){ A=in_w; aoff=CC;   Bm=wk;    bs=bk;    ba=in_b;   boff=CC;   }
  else if (mat==2){ A=in_w; aoff=2*CC; Bm=wv;    bs=bv;    ba=in_b;   boff=2*CC; }
  else            { A=proj_w; aoff=0;  Bm=out_w; bs=out_b; ba=proj_b; boff=0;    }
  const float* ar = A + (size_t)(aoff + o) * CC;
  float acc = 0.f;
  for (int m = 0; m < CC; ++m) acc = fmaf(ar[m], Bm[m*CC + ci], acc);
  int k = ci >> 5, n = o >> 4, lgv = (ci >> 3) & 3, e = ci & 7;
  int lane = (o & 15) | (lgv << 4);
  Wf[(((mat*6 + k)*12 + n) << 9) + lane*8 + e] = f2b(acc * scale);
  if (ci == 0){
    float bacc = 0.f;
    for (int m = 0; m < CC; ++m) bacc = fmaf(ar[m], bs[m], bacc);
    Bf[mat*CC + o] = (bacc + ba[boff + o]) * scale;
  }
}

__global__ __launch_bounds__(256, 2) void win_attn(
    const float* __restrict__ q2d, const float* __restrict__ kv2d,
    const unsigned short* __restrict__ Wf, const float* __restrict__ Bf,
    float* __restrict__ out)
{
  __shared__ unsigned short B1[64*SX];   // Xq -> Q -> O   [tok][ch]
  __shared__ unsigned short B2[64*SX];   // Xkv -> K       [tok][ch]
  __shared__ unsigned short VT[192*72];  // V^T [ch][tok]

  const int t = threadIdx.x;
  const int w = t >> 6, lane = t & 63, lr = lane & 15, lg = lane >> 4;
  const int bid = blockIdx.x;
  const int wid = (bid & 7) * 512 + (bid >> 3);   // XCD-chunked, bijective
  const int b = wid >> 10, l = wid & 1023;
  const int y0 = (l >> 5) << 3, x0 = (l & 31) << 3;
  const float* qsrc  = q2d  + (size_t)b * CC * 65536;
  const float* kvsrc = kv2d + (size_t)b * CC * 65536;
  const int n0 = w * 3;   // this wave's fixed 3-tile (48-channel) slice

  auto stage = [&](const float* __restrict__ src, unsigned short* __restrict__ dst){
    #pragma unroll
    for (int i = 0; i < 6; ++i){
      int lin = i*256 + t;
      int c2 = lin >> 4, tok0 = (lin & 15) << 2;
      int gy = (y0 + (tok0 >> 3)) * 256 + x0 + (tok0 & 7);
      float4 va = *(const float4*)&src[(size_t)(2*c2)   * 65536 + gy];
      float4 vb = *(const float4*)&src[(size_t)(2*c2+1) * 65536 + gy];
      float fa[4] = {va.x, va.y, va.z, va.w};
      float fb[4] = {vb.x, vb.y, vb.z, vb.w};
      #pragma unroll
      for (int j = 0; j < 4; ++j)
        *(unsigned*)&dst[(tok0 + j)*SX + 2*c2] = pk2(fa[j], fb[j]);
    }
  };

  stage(qsrc, B1);
  stage(kvsrc, B2);
  __syncthreads();

  // ---- projections (A-frags from X, B-frags = packed weights) ----
  // Generic: read Xs, return acc[u][m] for this wave's 3 channel tiles.
  auto projAcc = [&](const unsigned short* __restrict__ Xs, int mat, f32x4 (&acc)[3][4]){
    #pragma unroll
    for (int k = 0; k < 6; ++k){
      bf16x8 a[4];
      #pragma unroll
      for (int m = 0; m < 4; ++m)
        a[m] = *(const bf16x8*)&Xs[(m*16 + lr)*SX + k*32 + lg*8];
      #pragma unroll
      for (int u = 0; u < 3; ++u){
        bf16x8 bw = *(const bf16x8*)&Wf[(((mat*6 + k)*12 + n0 + u) << 9) + lane*8];
        #pragma unroll
        for (int m = 0; m < 4; ++m)
          acc[u][m] = __builtin_amdgcn_mfma_f32_16x16x32_bf16(a[m], bw, acc[u][m], 0, 0, 0);
      }
    }
  };

  f32x4 qacc[3][4] = {};
  projAcc(B1, 0, qacc);
  { // V projection -> VT immediately (VT not aliased)
    f32x4 vacc[3][4] = {};
    projAcc(B2, 2, vacc);
    #pragma unroll
    for (int u = 0; u < 3; ++u){
      int row = (n0 + u)*16 + lr;
      float bb = Bf[2*CC + row];
      #pragma unroll
      for (int m = 0; m < 4; ++m){
        *(unsigned*)&VT[row*72 + m*16 + lg*4]     = pk2(vacc[u][m][0] + bb, vacc[u][m][1] + bb);
        *(unsigned*)&VT[row*72 + m*16 + lg*4 + 2] = pk2(vacc[u][m][2] + bb, vacc[u][m][3] + bb);
      }
    }
  }
  f32x4 kacc[3][4] = {};
  projAcc(B2, 1, kacc);
  __syncthreads();            // all X reads done; B1/B2 reusable

  // write Q -> B1, K -> B2
  #pragma unroll
  for (int u = 0; u < 3; ++u){
    int ch = (n0 + u)*16 + lr;
    float bq_ = Bf[0*CC + ch], bk_ = Bf[1*CC + ch];
    #pragma unroll
    for (int m = 0; m < 4; ++m)
      #pragma unroll
      for (int rr = 0; rr < 4; ++rr){
        B1[(m*16 + lg*4 + rr)*SX + ch] = f2b(qacc[u][m][rr] + bq_);
        B2[(m*16 + lg*4 + rr)*SX + ch] = f2b(kacc[u][m][rr] + bk_);
      }
  }
  __syncthreads();

  // ---- attention: wave w owns q-rows r0..r0+15, all 6 heads; P in regs ----
  {
    const int r0 = w * 16;
    #pragma unroll
    for (int h = 0; h < 6; ++h){
      f32x4 st[4] = {};
      bf16x8 bq_ = *(const bf16x8*)&B1[(r0 + lr)*SX + h*32 + lg*8];
      #pragma unroll
      for (int m = 0; m < 4; ++m){
        bf16x8 a = *(const bf16x8*)&B2[(m*16 + lr)*SX + h*32 + lg*8];
        st[m] = __builtin_amdgcn_mfma_f32_16x16x32_bf16(a, bq_, st[m], 0, 0, 0);
      }
      // wave-parallel softmax over t2: 16 vals/lane, lanes lg share q-row lr
      float mx = st[0][0];
      #pragma unroll
      for (int m = 0; m < 4; ++m)
        #pragma unroll
        for (int rr = 0; rr < 4; ++rr) mx = fmaxf(mx, st[m][rr]);
      mx = fmaxf(mx, __shfl_xor(mx, 16));
      mx = fmaxf(mx, __shfl_xor(mx, 32));
      float p[16]; float s = 0.f;
      #pragma unroll
      for (int m = 0; m < 4; ++m)
        #pragma unroll
        for (int rr = 0; rr < 4; ++rr){ float e = __expf(st[m][rr] - mx); p[m*4+rr] = e; s += e; }
      s += __shfl_xor(s, 16); s += __shfl_xor(s, 32);
      float inv = 1.f / s;
      #pragma unroll
      for (int i2 = 0; i2 < 16; ++i2) p[i2] *= inv;
      // PV with permuted k-order: A-frag(kt) = lane's own p[8kt..8kt+7];
      // B-frag(kt) = VT[ch][kt*32+lg*4] (4) ++ VT[ch][kt*32+16+lg*4] (4).
      f32x4 o0 = {}, o1 = {};
      #pragma unroll
      for (int kt = 0; kt < 2; ++kt){
        bf16x8 ap;
        ((unsigned*)&ap)[0] = pk2(p[8*kt+0], p[8*kt+1]);
        ((unsigned*)&ap)[1] = pk2(p[8*kt+2], p[8*kt+3]);
        ((unsigned*)&ap)[2] = pk2(p[8*kt+4], p[8*kt+5]);
        ((unsigned*)&ap)[3] = pk2(p[8*kt+6], p[8*kt+7]);
        bf16x8 v0, v1;
        ((uint2*)&v0)[0] = *(const uint2*)&VT[(h*32 + lr)*72      + kt*32 + lg*4];
        ((uint2*)&v0)[1] = *(const uint2*)&VT[(h*32 + lr)*72      + kt*32 + 16 + lg*4];
        ((uint2*)&v1)[0] = *(const uint2*)&VT[(h*32 + 16 + lr)*72 + kt*32 + lg*4];
        ((uint2*)&v1)[1] = *(const uint2*)&VT[(h*32 + 16 + lr)*72 + kt*32 + 16 + lg*4];
        o0 = __builtin_amdgcn_mfma_f32_16x16x32_bf16(ap, v0, o0, 0, 0, 0);
        o1 = __builtin_amdgcn_mfma_f32_16x16x32_bf16(ap, v1, o1, 0, 0, 0);
      }
      // O overwrites Q in-place (same rows/chs consumed this iteration)
      #pragma unroll
      for (int rr = 0; rr < 4; ++rr){
        int tok = r0 + lg*4 + rr;
        B1[tok*SX + h*32 + lr]      = f2b(o0[rr]);
        B1[tok*SX + h*32 + 16 + lr] = f2b(o1[rr]);
      }
    }
  }
  __syncthreads();

  // ---- out-proj: E2^T = Wo_f * O^T; wave w owns out-channel tiles n0..n0+2 ----
  {
    f32x4 eo[3][4] = {};
    #pragma unroll
    for (int k = 0; k < 6; ++k){
      bf16x8 bo[4];
      #pragma unroll
      for (int nt = 0; nt < 4; ++nt)
        bo[nt] = *(const bf16x8*)&B1[(nt*16 + lr)*SX + k*32 + lg*8];
      #pragma unroll
      for (int u = 0; u < 3; ++u){
        bf16x8 aw = *(const bf16x8*)&Wf[(((18 + k)*12 + n0 + u) << 9) + lane*8];
        #pragma unroll
        for (int nt = 0; nt < 4; ++nt)
          eo[u][nt] = __builtin_amdgcn_mfma_f32_16x16x32_bf16(aw, bo[nt], eo[u][nt], 0, 0, 0);
      }
    }
    #pragma unroll
    for (int u = 0; u < 3; ++u){
      #pragma unroll
      for (int rr = 0; rr < 4; ++rr){
        int o = (n0 + u)*16 + lg*4 + rr;
        float bb = Bf[3*CC + o];
        #pragma unroll
        for (int nt = 0; nt < 4; ++nt){
          int tok = nt*16 + lr;
          size_t g = (size_t)(b*CC + o)*65536 + (size_t)(y0 + (tok >> 3))*256 + x0 + (tok & 7);
          out[g] = eo[u][nt][rr] + bb + q2d[g];
        }
      }
    }
  }
}

extern "C" void kernel_launch(void* const* d_in, const int* in_sizes, int n_in,
                              void* d_out, int out_size, void* d_ws, size_t ws_size,
                              hipStream_t stream)
{
  const float* q2d    = (const float*)d_in[0];
  const float* kv2d   = (const float*)d_in[1];
  const float* wq     = (const float*)d_in[2];
  const float* bq     = (const float*)d_in[3];
  const float* wk     = (const float*)d_in[4];
  const float* bk     = (const float*)d_in[5];
  const float* wv     = (const float*)d_in[6];
  const float* bv     = (const float*)d_in[7];
  const float* in_w   = (const float*)d_in[8];
  const float* in_b   = (const float*)d_in[9];
  const float* out_w  = (const float*)d_in[10];
  const float* out_b  = (const float*)d_in[11];
  const float* proj_w = (const float*)d_in[12];
  const float* proj_b = (const float*)d_in[13];

  unsigned short* Wf = (unsigned short*)d_ws;
  float* Bf = (float*)((char*)d_ws + WFRAG_USHORTS*2);
  float* out = (float*)d_out;

  fuse_weights<<<4*CC, CC, 0, stream>>>(wq,bq,wk,bk,wv,bv,in_w,in_b,
                                        out_w,out_b,proj_w,proj_b, Wf, Bf);
  win_attn<<<4096, 256, 0, stream>>>(q2d, kv2d, Wf, Bf, out);
}